// Round 1
// baseline (122.763 us; speedup 1.0000x reference)
//
#include <hip/hip_runtime.h>

#define NB 8
#define NS 2048
#define ND 64
#define LOG2E 1.44269504f
// int16 Q8.8 logit cache: step 2^-9 in log2-units (~0.07% rel on p), range +-128
#define QSC 256.0f
#define IQS (1.0f / 256.0f)

typedef _Float16 half8 __attribute__((ext_vector_type(8)));
typedef short short8 __attribute__((ext_vector_type(8)));
typedef __attribute__((ext_vector_type(4))) float floatx4;

__device__ __forceinline__ half8 cvt8(const float* p) {
    float4 a = *(const float4*)p;
    float4 b = *(const float4*)(p + 4);
    half8 h = {(_Float16)a.x, (_Float16)a.y, (_Float16)a.z, (_Float16)a.w,
               (_Float16)b.x, (_Float16)b.y, (_Float16)b.z, (_Float16)b.w};
    return h;
}
__device__ __forceinline__ half8 cvtWcol(const float* base) {
    half8 h;
#pragma unroll
    for (int j = 0; j < 8; ++j) h[j] = (_Float16)base[j * 64];
    return h;
}

// ---------------- QKV projection via fp16 MFMA (unchanged) -------------------
__global__ __launch_bounds__(256) void qkv_proj(
    const float* __restrict__ x,
    const float* __restrict__ Wq, const float* __restrict__ bq,
    const float* __restrict__ Wk, const float* __restrict__ bk,
    const float* __restrict__ Wv, const float* __restrict__ bv,
    _Float16* __restrict__ Qg, _Float16* __restrict__ Kg,
    _Float16* __restrict__ Vt)
{
    __shared__ _Float16 vt[64 * 18];

    const int tid  = threadIdx.x;
    const int wv   = tid >> 6;
    const int l    = tid & 63;
    const int quad = l >> 4;
    const int tx   = l & 15;

    const int b  = blockIdx.x & 7;
    const int n0 = (blockIdx.x >> 3) * 16;

    const float* xr = x + ((size_t)b * NS + n0 + tx) * ND + quad * 8;
    half8 a0 = cvt8(xr);
    half8 a1 = cvt8(xr + 32);

    const floatx4 zf = {0.f, 0.f, 0.f, 0.f};

#pragma unroll
    for (int i = 0; i < 3; ++i) {
        const int ct = wv * 3 + i;
        const int m  = ct >> 2;
        const int lcol = (ct & 3) * 16 + tx;

        const float* Wm;
        const float* Bm;
        if (m == 0)      { Wm = Wq; Bm = bq; }
        else if (m == 1) { Wm = Wk; Bm = bk; }
        else             { Wm = Wv; Bm = bv; }

        half8 b0 = cvtWcol(Wm + (quad * 8) * 64 + lcol);
        half8 b1 = cvtWcol(Wm + (32 + quad * 8) * 64 + lcol);

        floatx4 acc = __builtin_amdgcn_mfma_f32_16x16x32_f16(a0, b0, zf, 0, 0, 0);
        acc = __builtin_amdgcn_mfma_f32_16x16x32_f16(a1, b1, acc, 0, 0, 0);
        const float bias = Bm[lcol];

        if (m == 0) {
#pragma unroll
            for (int r = 0; r < 4; ++r)
                Qg[((size_t)b * NS + n0 + quad * 4 + r) * ND + lcol] =
                    (_Float16)((acc[r] + bias) * LOG2E);
        } else if (m == 1) {
#pragma unroll
            for (int r = 0; r < 4; ++r)
                Kg[((size_t)b * NS + n0 + quad * 4 + r) * ND + lcol] = (_Float16)(acc[r] + bias);
        } else {
#pragma unroll
            for (int r = 0; r < 4; ++r)
                vt[lcol * 18 + quad * 4 + r] = (_Float16)(acc[r] + bias);
        }
    }
    __syncthreads();
    {
        const int d = tid >> 2, seg = tid & 3;
        uint2 p = *(uint2*)&vt[d * 18 + seg * 4];
        *(uint2*)(Vt + ((size_t)b * ND + d) * NS + n0 + seg * 4) = p;
    }
}

// ---------------- fused masked attention with int16 logit cache --------------
// Pass 1 (32 x 64-key tiles, K LDS-staged, 1 barrier/tile): SWAPPED QK MFMA
//   mfma(kf, qf) -> D[key][q-row]; thread holds 4 consecutive keys of one row
//   -> quantize c*256 -> int16, ONE 8B coalesced global store per rh per tile
//   into ct[row][key]. L accumulated from the QUANTIZED scores (consistent
//   softmax: quantization cancels where p is large). lacc is per-row scalar;
//   quad-reduce via shfl_xor(16/32), kq-merge via lsh.
// Pass 2 (16 x 128-key tiles, V LDS-staged, 1 barrier/tile): NO QK recompute,
//   NO psm exchange. Waves split keys 4-ways (kq). A-frag = short8 from ct
//   (16B, L2-hot, prefetched 1 tile ahead); mask+exp in-register:
//   w = (c~ - lg2L > -11) ? exp2 : 0   [p > 1/N <=> c > lg2L - log2(N)]
//   PV accumulates rows(h,rt) x all 64 dims over the wave's key quarter;
//   4-step LDS merge over kq at the end. Barriers: 96 -> 53.
__global__ __launch_bounds__(512, 2) void attn(
    const _Float16* __restrict__ Qg,
    const _Float16* __restrict__ Kg,
    const _Float16* __restrict__ Vt,
    short* __restrict__ ct,
    float* __restrict__ out)
{
    // union: pass1 ksm[2][64][72] (18.4KB) | pass2 vsm[2][64][136] (34.8KB)
    //        | merge osm[64][68] f32 (17.4KB)
    __shared__ __align__(16) _Float16 smem[2 * 64 * 136];
    __shared__ float lsh[4 * 64];

    const int tid  = threadIdx.x;
    const int wv   = tid >> 6;
    const int l    = tid & 63;
    const int quad = l >> 4;
    const int tx   = l & 15;
    const int h    = wv >> 2;       // q-half (32 rows)
    const int kq   = wv & 3;        // key-quarter (both passes)

    const int b  = blockIdx.x & 7;
    const int q0 = (blockIdx.x >> 3) * 64;

    const _Float16* Qb = Qg + ((size_t)b * NS + q0 + h * 32) * ND;
    const _Float16* Kb = Kg + (size_t)b * NS * ND;
    const _Float16* Vb = Vt + (size_t)b * ND * NS;
    short* ctb = ct + ((size_t)b * NS + q0) * NS;   // [64 rows][2048 keys]

    // Q B-frags: rows h*32 + rh*16 + tx, k-chunks 0/1
    half8 qf[2][2];
#pragma unroll
    for (int rh = 0; rh < 2; ++rh)
#pragma unroll
        for (int kc = 0; kc < 2; ++kc)
            qf[rh][kc] = *(const half8*)(Qb + (size_t)(rh * 16 + tx) * ND + kc * 32 + quad * 8);

    const floatx4 zf = {0.f, 0.f, 0.f, 0.f};

    // ================= pass 1: L + logit cache =================
    {
        const int skey = tid >> 3;              // staged key
        const int sc   = (tid & 7) * 8;
        const _Float16* Ksrc = Kb + (size_t)skey * ND + sc;
        const int sdst = skey * 72 + sc;
        const int krow = (kq * 16 + tx) * 72;   // A-frag key row base

        short* cst0 = ctb + (size_t)(h * 32 + tx) * NS + kq * 16 + quad * 4;
        short* cst1 = cst0 + (size_t)16 * NS;

        float lacc0 = 0.f, lacc1 = 0.f;

        uint4 gk = *(const uint4*)Ksrc;
        *(uint4*)(smem + sdst) = gk;
        for (int t = 0; t < 32; ++t) {
            const int buf = (t & 1) * 4608;
            __syncthreads();
            if (t < 31) gk = *(const uint4*)(Ksrc + (size_t)(t + 1) * 64 * ND);
            half8 kf0 = *(const half8*)(smem + buf + krow + quad * 8);
            half8 kf1 = *(const half8*)(smem + buf + krow + 32 + quad * 8);
#pragma unroll
            for (int rh = 0; rh < 2; ++rh) {
                floatx4 c = __builtin_amdgcn_mfma_f32_16x16x32_f16(kf0, qf[rh][0], zf, 0, 0, 0);
                c = __builtin_amdgcn_mfma_f32_16x16x32_f16(kf1, qf[rh][1], c, 0, 0, 0);
                int ci[4];
                float ladd = 0.f;
#pragma unroll
                for (int r = 0; r < 4; ++r) {
                    float cs = fminf(fmaxf(c[r] * QSC, -32767.f), 32767.f);
                    int ic = (int)rintf(cs);
                    ci[r] = ic;
                    ladd += __builtin_amdgcn_exp2f((float)ic * IQS);  // quantized-consistent L
                }
                if (rh == 0) lacc0 += ladd; else lacc1 += ladd;
                uint2 pk;
                pk.x = (unsigned)(ci[0] & 0xffff) | ((unsigned)(ci[1] & 0xffff) << 16);
                pk.y = (unsigned)(ci[2] & 0xffff) | ((unsigned)(ci[3] & 0xffff) << 16);
                *(uint2*)((rh ? cst1 : cst0) + (size_t)t * 64) = pk;
            }
            if (t < 31) *(uint4*)(smem + (buf ^ 4608) + sdst) = gk;
        }

        // reduce over quads (lanes tx, tx+16, tx+32, tx+48 share a row)
#pragma unroll
        for (int off = 16; off < 64; off <<= 1) {
            lacc0 += __shfl_xor(lacc0, off);
            lacc1 += __shfl_xor(lacc1, off);
        }
        if (quad == 0) {
            lsh[kq * 64 + h * 32 + tx]      = lacc0;
            lsh[kq * 64 + h * 32 + 16 + tx] = lacc1;
        }
    }

    // pass-2 staging roles: V^T tiles of 128 keys, vsm[dim][136]
    const int sdim = tid >> 4;
    const int sseg = (tid & 15) * 8;
    const _Float16* Vsrc0 = Vb + (size_t)sdim * NS + sseg;
    const _Float16* Vsrc1 = Vb + (size_t)(sdim + 32) * NS + sseg;
    const int vdst0 = sdim * 136 + sseg;
    const int vdst1 = (sdim + 32) * 136 + sseg;

    // ct A-frag pointers: row h*32 + rt*16 + tx, keys kq*32 + quad*8 (+ t*128)
    const short* crd0 = ctb + (size_t)(h * 32 + tx) * NS + kq * 32 + quad * 8;
    const short* crd1 = crd0 + (size_t)16 * NS;

    // prefetch tile 0 (overlaps the merge barrier)
    uint4 gv0 = *(const uint4*)Vsrc0;
    uint4 gv1 = *(const uint4*)Vsrc1;
    short8 ca0 = *(const short8*)crd0;
    short8 ca1 = *(const short8*)crd1;

    __syncthreads();        // lsh ready; all pass-1 smem reads done (reuse safe)

    float lg2L0, lg2L1;
    {
        const int row = h * 32 + tx;
        float L0 = lsh[row] + lsh[64 + row] + lsh[128 + row] + lsh[192 + row];
        float L1 = lsh[row + 16] + lsh[64 + row + 16] + lsh[128 + row + 16] + lsh[192 + row + 16];
        lg2L0 = __builtin_amdgcn_logf(L0);      // v_log_f32 = log2
        lg2L1 = __builtin_amdgcn_logf(L1);
    }

    *(uint4*)(smem + vdst0) = gv0;
    *(uint4*)(smem + vdst1) = gv1;

    floatx4 o[2][4] = {{zf, zf, zf, zf}, {zf, zf, zf, zf}};

    // ================= pass 2: mask + PV =================
    for (int t = 0; t < 16; ++t) {
        const int buf = (t & 1) * 8704;         // 64*136 halfs
        __syncthreads();                        // tile staged & visible
        short8 cn0, cn1;
        if (t < 15) {
            gv0 = *(const uint4*)(Vsrc0 + (size_t)(t + 1) * 128);
            gv1 = *(const uint4*)(Vsrc1 + (size_t)(t + 1) * 128);
            cn0 = *(const short8*)(crd0 + (size_t)(t + 1) * 128);
            cn1 = *(const short8*)(crd1 + (size_t)(t + 1) * 128);
        }
        half8 a0, a1;
#pragma unroll
        for (int j = 0; j < 8; ++j) {
            float d0 = (float)ca0[j] * IQS - lg2L0;
            a0[j] = (d0 > -11.f) ? (_Float16)__builtin_amdgcn_exp2f(d0) : (_Float16)0.f;
            float d1 = (float)ca1[j] * IQS - lg2L1;
            a1[j] = (d1 > -11.f) ? (_Float16)__builtin_amdgcn_exp2f(d1) : (_Float16)0.f;
        }
#pragma unroll
        for (int dg = 0; dg < 4; ++dg) {
            half8 vf = *(const half8*)(smem + buf + (dg * 16 + tx) * 136 + kq * 32 + quad * 8);
            o[0][dg] = __builtin_amdgcn_mfma_f32_16x16x32_f16(a0, vf, o[0][dg], 0, 0, 0);
            o[1][dg] = __builtin_amdgcn_mfma_f32_16x16x32_f16(a1, vf, o[1][dg], 0, 0, 0);
        }
        if (t < 15) {
            *(uint4*)(smem + (buf ^ 8704) + vdst0) = gv0;
            *(uint4*)(smem + (buf ^ 8704) + vdst1) = gv1;
            ca0 = cn0; ca1 = cn1;
        }
    }

    // ================= merge key-quarter partials, store =================
    __syncthreads();                            // all vsm reads done
    float* osm = (float*)smem;                  // [64][68]
    if (kq == 0) {
#pragma unroll
        for (int rt = 0; rt < 2; ++rt)
#pragma unroll
            for (int dg = 0; dg < 4; ++dg)
#pragma unroll
                for (int r = 0; r < 4; ++r)
                    osm[(h * 32 + rt * 16 + quad * 4 + r) * 68 + dg * 16 + tx] = o[rt][dg][r];
    }
    __syncthreads();
    if (kq == 1) {
#pragma unroll
        for (int rt = 0; rt < 2; ++rt)
#pragma unroll
            for (int dg = 0; dg < 4; ++dg)
#pragma unroll
                for (int r = 0; r < 4; ++r)
                    osm[(h * 32 + rt * 16 + quad * 4 + r) * 68 + dg * 16 + tx] += o[rt][dg][r];
    }
    __syncthreads();
    if (kq == 2) {
#pragma unroll
        for (int rt = 0; rt < 2; ++rt)
#pragma unroll
            for (int dg = 0; dg < 4; ++dg)
#pragma unroll
                for (int r = 0; r < 4; ++r)
                    osm[(h * 32 + rt * 16 + quad * 4 + r) * 68 + dg * 16 + tx] += o[rt][dg][r];
    }
    __syncthreads();
    if (kq == 3) {
#pragma unroll
        for (int rt = 0; rt < 2; ++rt)
#pragma unroll
            for (int dg = 0; dg < 4; ++dg)
#pragma unroll
                for (int r = 0; r < 4; ++r)
                    out[((size_t)b * NS + q0 + h * 32 + rt * 16 + quad * 4 + r) * ND + dg * 16 + tx] =
                        osm[(h * 32 + rt * 16 + quad * 4 + r) * 68 + dg * 16 + tx] + o[rt][dg][r];
    }
}

extern "C" void kernel_launch(void* const* d_in, const int* in_sizes, int n_in,
                              void* d_out, int out_size, void* d_ws, size_t ws_size,
                              hipStream_t stream) {
    const float* x  = (const float*)d_in[0];
    const float* Wq = (const float*)d_in[1];
    const float* bq = (const float*)d_in[2];
    const float* Wk = (const float*)d_in[3];
    const float* bk = (const float*)d_in[4];
    const float* Wv = (const float*)d_in[5];
    const float* bv = (const float*)d_in[6];

    // ws layout: Qg(2MB) Kg(2MB) Vt(2MB) ct(64MB int16) -- ws_size is 256MiB
    _Float16* Qg = (_Float16*)d_ws;
    _Float16* Kg = Qg + (size_t)NB * NS * ND;
    _Float16* Vt = Kg + (size_t)NB * NS * ND;
    short*    ct = (short*)(Vt + (size_t)NB * NS * ND);

    qkv_proj<<<NB * (NS / 16), 256, 0, stream>>>(x, Wq, bq, Wk, bk, Wv, bv, Qg, Kg, Vt);
    attn<<<NB * (NS / 64), 512, 0, stream>>>(Qg, Kg, Vt, ct, (float*)d_out);
}

// Round 3
// 112.379 us; speedup vs baseline: 1.0924x; 1.0924x over previous
//
#include <hip/hip_runtime.h>

#define NB 8
#define NS 2048
#define ND 64
#define LOG2E 1.44269504f

typedef _Float16 half8 __attribute__((ext_vector_type(8)));
typedef _Float16 half4 __attribute__((ext_vector_type(4)));
typedef __attribute__((ext_vector_type(4))) float floatx4;

__device__ __forceinline__ half8 cvt8(const float* p) {
    float4 a = *(const float4*)p;
    float4 b = *(const float4*)(p + 4);
    half8 h = {(_Float16)a.x, (_Float16)a.y, (_Float16)a.z, (_Float16)a.w,
               (_Float16)b.x, (_Float16)b.y, (_Float16)b.z, (_Float16)b.w};
    return h;
}

// ---------------- W prep: fp32 [d][c] -> fp16 Wt[m][c][d] (B-frag friendly) --
__global__ __launch_bounds__(256) void wprep(
    const float* __restrict__ Wq, const float* __restrict__ Wk,
    const float* __restrict__ Wv, _Float16* __restrict__ Wt)
{
    const int m = blockIdx.x;
    const float* W = (m == 0) ? Wq : (m == 1) ? Wk : Wv;
    for (int i = threadIdx.x; i < 64 * 64; i += 256) {
        const int c = i >> 6, d = i & 63;
        Wt[((size_t)m * 64 + c) * 64 + d] = (_Float16)W[d * 64 + c];
    }
}

// ---------------- QKV projection: 64 rows/block, vector fp16 W loads ---------
__global__ __launch_bounds__(256) void qkv_proj(
    const float* __restrict__ x, const _Float16* __restrict__ Wt,
    const float* __restrict__ bq, const float* __restrict__ bk,
    const float* __restrict__ bv,
    _Float16* __restrict__ Qg, _Float16* __restrict__ Kg,
    _Float16* __restrict__ Vt)
{
    __shared__ _Float16 vt[4][64 * 20];   // per-wave V^T staging [col][row], 10.2KB

    const int tid  = threadIdx.x;
    const int wv   = tid >> 6;
    const int l    = tid & 63;
    const int quad = l >> 4;
    const int tx   = l & 15;

    const int b  = blockIdx.x & 7;                  // XCD-pinned batch
    const int n0 = (blockIdx.x >> 3) * 64 + wv * 16;

    const float* xr = x + ((size_t)b * NS + n0 + tx) * ND + quad * 8;
    half8 a0 = cvt8(xr);
    half8 a1 = cvt8(xr + 32);

    const floatx4 zf = {0.f, 0.f, 0.f, 0.f};

#pragma unroll
    for (int ctile = 0; ctile < 12; ++ctile) {
        const int m    = ctile >> 2;
        const int lcol = (ctile & 3) * 16 + tx;

        const _Float16* Wb = Wt + ((size_t)m * 64 + lcol) * 64;
        half8 b0 = *(const half8*)(Wb + quad * 8);
        half8 b1 = *(const half8*)(Wb + 32 + quad * 8);

        floatx4 acc = __builtin_amdgcn_mfma_f32_16x16x32_f16(a0, b0, zf, 0, 0, 0);
        acc = __builtin_amdgcn_mfma_f32_16x16x32_f16(a1, b1, acc, 0, 0, 0);

        const float* Bp = (m == 0) ? bq : (m == 1) ? bk : bv;
        const float bias = Bp[lcol];

        if (m == 0) {
#pragma unroll
            for (int r = 0; r < 4; ++r)
                Qg[((size_t)b * NS + n0 + quad * 4 + r) * ND + lcol] =
                    (_Float16)((acc[r] + bias) * LOG2E);
        } else if (m == 1) {
#pragma unroll
            for (int r = 0; r < 4; ++r)
                Kg[((size_t)b * NS + n0 + quad * 4 + r) * ND + lcol] =
                    (_Float16)(acc[r] + bias);
        } else {
#pragma unroll
            for (int r = 0; r < 4; ++r)
                vt[wv][lcol * 20 + quad * 4 + r] = (_Float16)(acc[r] + bias);
        }
    }
    __syncthreads();
    {
        const int d = l;
        const _Float16* src = &vt[wv][d * 20];
        uint2 p0 = *(const uint2*)(src);
        uint2 p1 = *(const uint2*)(src + 4);
        uint2 p2 = *(const uint2*)(src + 8);
        uint2 p3 = *(const uint2*)(src + 12);
        uint4 q0 = {p0.x, p0.y, p1.x, p1.y};
        uint4 q1 = {p2.x, p2.y, p3.x, p3.y};
        _Float16* dst = Vt + ((size_t)b * ND + d) * NS + n0;
        *(uint4*)(dst)     = q0;
        *(uint4*)(dst + 8) = q1;
    }
}

// ---------------- fused masked attention: zero-exchange PV -------------------
// Pass 1 (32 x 64-key tiles, K LDS-staged, 1 barrier/tile): swapped QK
//   mfma(kf, qf) -> lane(quad,tx) reg r = score[key=kq*16+quad*4+r][qrow=tx];
//   lacc += exp2(c).  Reduce over quads (shfl_xor 16/32), merge kq via lsh.
// Pass 2 (32 x 64-key tiles, K+V^T LDS-staged, 1 barrier/tile): recompute
//   scores (swapped), mask+normalize in-register:
//     e = exp2(c); w = e > L/N ? e/L : 0
//   KEY IDENTITY: the swapped-QK D-layout IS the A-frag layout of
//   v_mfma_f32_16x16x16_f16 (A[m=l&15][k=quad*4+j]) -> P feeds PV directly
//   from registers. No psm exchange, no 2nd barrier. B-frag = single
//   ds_read_b64 from vsmT[dim][key] (stride 72: 2-way banks = free).
//   o[rh][dg] covers rows h*32+rh*16, dims dg*16, wave's key-quarter;
//   4-step LDS merge over kq at the end. Barriers: 97 -> 69.
__global__ __launch_bounds__(512, 2) void attn(
    const _Float16* __restrict__ Qg,
    const _Float16* __restrict__ Kg,
    const _Float16* __restrict__ Vt,
    float* __restrict__ out)
{
    __shared__ __align__(16) _Float16 smem[2 * 64 * 72 + 2 * 64 * 72]; // ksm|vsm, 36.9KB
    __shared__ float lsh[4 * 64];

    _Float16* ksm = smem;
    _Float16* vsm = smem + 2 * 64 * 72;

    const int tid  = threadIdx.x;
    const int wv   = tid >> 6;
    const int l    = tid & 63;
    const int quad = l >> 4;
    const int tx   = l & 15;
    const int h    = wv >> 2;       // q-half (32 rows)
    const int kq   = wv & 3;        // key-quarter

    const int b  = blockIdx.x & 7;
    const int q0 = (blockIdx.x >> 3) * 64;

    const _Float16* Qb = Qg + ((size_t)b * NS + q0 + h * 32) * ND;
    const _Float16* Kb = Kg + (size_t)b * NS * ND;
    const _Float16* Vb = Vt + (size_t)b * ND * NS;

    // Q B-frags: rows h*32 + rh*16 + tx, k-chunks 0/1
    half8 qf[2][2];
#pragma unroll
    for (int rh = 0; rh < 2; ++rh)
#pragma unroll
        for (int kc = 0; kc < 2; ++kc)
            qf[rh][kc] = *(const half8*)(Qb + (size_t)(rh * 16 + tx) * ND + kc * 32 + quad * 8);

    // staging roles: thread -> 16B of each 8KB tile
    const int skey = tid >> 3;
    const int sc   = (tid & 7) * 8;
    const _Float16* Ksrc = Kb + (size_t)skey * ND + sc;   // + t*64*ND
    const _Float16* Vsrc = Vb + (size_t)skey * NS + sc;   // + t*64   (skey = dim here)
    const int kdst = skey * 72 + sc;

    const floatx4 zf = {0.f, 0.f, 0.f, 0.f};
    const int krow = (kq * 16 + tx) * 72;   // K A-frag row base

    // ================= pass 1: L =================
    float lacc0 = 0.f, lacc1 = 0.f;
    {
        uint4 gk = *(const uint4*)Ksrc;
        *(uint4*)(ksm + kdst) = gk;
        for (int t = 0; t < 32; ++t) {
            const int buf = (t & 1) * 4608;
            __syncthreads();
            if (t < 31) gk = *(const uint4*)(Ksrc + (size_t)(t + 1) * 64 * ND);
            half8 kf0 = *(const half8*)(ksm + buf + krow + quad * 8);
            half8 kf1 = *(const half8*)(ksm + buf + krow + 32 + quad * 8);
#pragma unroll
            for (int rh = 0; rh < 2; ++rh) {
                floatx4 c = __builtin_amdgcn_mfma_f32_16x16x32_f16(kf0, qf[rh][0], zf, 0, 0, 0);
                c = __builtin_amdgcn_mfma_f32_16x16x32_f16(kf1, qf[rh][1], c, 0, 0, 0);
                float ladd = __builtin_amdgcn_exp2f(c[0]) + __builtin_amdgcn_exp2f(c[1])
                           + __builtin_amdgcn_exp2f(c[2]) + __builtin_amdgcn_exp2f(c[3]);
                if (rh == 0) lacc0 += ladd; else lacc1 += ladd;
            }
            if (t < 31) *(uint4*)(ksm + (buf ^ 4608) + kdst) = gk;
        }
    }
    // reduce over quads (lanes tx, tx+16, tx+32, tx+48 share a q-row)
#pragma unroll
    for (int off = 16; off < 64; off <<= 1) {
        lacc0 += __shfl_xor(lacc0, off);
        lacc1 += __shfl_xor(lacc1, off);
    }
    if (quad == 0) {
        lsh[kq * 64 + h * 32 + tx]      = lacc0;
        lsh[kq * 64 + h * 32 + 16 + tx] = lacc1;
    }

    // transition: prefetch tile 0 (K + V) over the merge barrier
    uint4 gk = *(const uint4*)Ksrc;
    uint4 gv = *(const uint4*)Vsrc;
    __syncthreads();                                // lsh ready; pass-1 LDS reads done

    float thr0, inv0, thr1, inv1;
    {
        const int row = h * 32 + tx;
        float L0 = lsh[row] + lsh[64 + row] + lsh[128 + row] + lsh[192 + row];
        float L1 = lsh[row + 16] + lsh[64 + row + 16] + lsh[128 + row + 16] + lsh[192 + row + 16];
        inv0 = 1.f / L0;  thr0 = L0 * (1.f / (float)NS);
        inv1 = 1.f / L1;  thr1 = L1 * (1.f / (float)NS);
    }

    *(uint4*)(ksm + kdst) = gk;
    *(uint4*)(vsm + kdst) = gv;     // vsmT[dim][72] — same 16B-aligned layout

    floatx4 o[2][4] = {{zf, zf, zf, zf}, {zf, zf, zf, zf}};

    // ================= pass 2: recompute + mask + PV =================
    for (int t = 0; t < 32; ++t) {
        const int buf = (t & 1) * 4608;
        __syncthreads();                            // tiles staged & visible
        if (t < 31) {
            gk = *(const uint4*)(Ksrc + (size_t)(t + 1) * 64 * ND);
            gv = *(const uint4*)(Vsrc + (size_t)(t + 1) * 64);
        }
        half8 kf0 = *(const half8*)(ksm + buf + krow + quad * 8);
        half8 kf1 = *(const half8*)(ksm + buf + krow + 32 + quad * 8);
        // V B-frags: B[k=quad*4+j][n=tx] = vsmT[dg*16+tx][kq*16+quad*4 + j]
        half4 vf[4];
#pragma unroll
        for (int dg = 0; dg < 4; ++dg)
            vf[dg] = *(const half4*)(vsm + buf + (dg * 16 + tx) * 72 + kq * 16 + quad * 4);
#pragma unroll
        for (int rh = 0; rh < 2; ++rh) {
            floatx4 c = __builtin_amdgcn_mfma_f32_16x16x32_f16(kf0, qf[rh][0], zf, 0, 0, 0);
            c = __builtin_amdgcn_mfma_f32_16x16x32_f16(kf1, qf[rh][1], c, 0, 0, 0);
            const float thr = rh ? thr1 : thr0;
            const float inv = rh ? inv1 : inv0;
            float e0 = __builtin_amdgcn_exp2f(c[0]);
            float e1 = __builtin_amdgcn_exp2f(c[1]);
            float e2 = __builtin_amdgcn_exp2f(c[2]);
            float e3 = __builtin_amdgcn_exp2f(c[3]);
            float w0 = (e0 > thr) ? e0 * inv : 0.f;
            float w1 = (e1 > thr) ? e1 * inv : 0.f;
            float w2 = (e2 > thr) ? e2 * inv : 0.f;
            float w3 = (e3 > thr) ? e3 * inv : 0.f;
            half4 af = {(_Float16)w0, (_Float16)w1, (_Float16)w2, (_Float16)w3};
#pragma unroll
            for (int dg = 0; dg < 4; ++dg)
                o[rh][dg] = __builtin_amdgcn_mfma_f32_16x16x16f16(af, vf[dg], o[rh][dg], 0, 0, 0);
        }
        if (t < 31) {
            *(uint4*)(ksm + (buf ^ 4608) + kdst) = gk;
            *(uint4*)(vsm + (buf ^ 4608) + kdst) = gv;
        }
    }

    // ================= merge key-quarter partials, store =================
    __syncthreads();                                // all vsm reads done
    float* osm = (float*)smem;                      // [64][68] overlay
    if (kq == 0) {
#pragma unroll
        for (int rh = 0; rh < 2; ++rh)
#pragma unroll
            for (int dg = 0; dg < 4; ++dg)
#pragma unroll
                for (int r = 0; r < 4; ++r)
                    osm[(h * 32 + rh * 16 + quad * 4 + r) * 68 + dg * 16 + tx] = o[rh][dg][r];
    }
    __syncthreads();
    if (kq == 1) {
#pragma unroll
        for (int rh = 0; rh < 2; ++rh)
#pragma unroll
            for (int dg = 0; dg < 4; ++dg)
#pragma unroll
                for (int r = 0; r < 4; ++r)
                    osm[(h * 32 + rh * 16 + quad * 4 + r) * 68 + dg * 16 + tx] += o[rh][dg][r];
    }
    __syncthreads();
    if (kq == 2) {
#pragma unroll
        for (int rh = 0; rh < 2; ++rh)
#pragma unroll
            for (int dg = 0; dg < 4; ++dg)
#pragma unroll
                for (int r = 0; r < 4; ++r)
                    osm[(h * 32 + rh * 16 + quad * 4 + r) * 68 + dg * 16 + tx] += o[rh][dg][r];
    }
    __syncthreads();
    if (kq == 3) {
#pragma unroll
        for (int rh = 0; rh < 2; ++rh)
#pragma unroll
            for (int dg = 0; dg < 4; ++dg)
#pragma unroll
                for (int r = 0; r < 4; ++r)
                    out[((size_t)b * NS + q0 + h * 32 + rh * 16 + quad * 4 + r) * ND + dg * 16 + tx] =
                        osm[(h * 32 + rh * 16 + quad * 4 + r) * 68 + dg * 16 + tx] + o[rh][dg][r];
    }
}

extern "C" void kernel_launch(void* const* d_in, const int* in_sizes, int n_in,
                              void* d_out, int out_size, void* d_ws, size_t ws_size,
                              hipStream_t stream) {
    const float* x  = (const float*)d_in[0];
    const float* Wq = (const float*)d_in[1];
    const float* bq = (const float*)d_in[2];
    const float* Wk = (const float*)d_in[3];
    const float* bk = (const float*)d_in[4];
    const float* Wv = (const float*)d_in[5];
    const float* bv = (const float*)d_in[6];

    // ws: Qg(2MB) Kg(2MB) Vt(2MB) Wt(24KB)
    _Float16* Qg = (_Float16*)d_ws;
    _Float16* Kg = Qg + (size_t)NB * NS * ND;
    _Float16* Vt = Kg + (size_t)NB * NS * ND;
    _Float16* Wt = Vt + (size_t)NB * NS * ND;

    wprep<<<3, 256, 0, stream>>>(Wq, Wk, Wv, Wt);
    qkv_proj<<<NB * (NS / 64), 256, 0, stream>>>(x, Wt, bq, bk, bv, Qg, Kg, Vt);
    attn<<<NB * (NS / 64), 512, 0, stream>>>(Qg, Kg, Vt, (float*)d_out);
}